// Round 8
// baseline (395.955 us; speedup 1.0000x reference)
//
#include <hip/hip_runtime.h>

#define N_NODES 50000
#define N_EDGES 800000
#define IN_DIM  8
#define HD      128
#define N_SCAN_BLOCKS ((N_NODES + 255) / 256)   // 196
#define NREP 16
#define NTILES ((N_NODES + 63) / 64)            // 782 row-tiles of 64
#define N_HIST_BLOCKS (N_EDGES / 256)           // 3125
#define GRID 512                                 // co-resident @ 2 blocks/CU

typedef unsigned short ushort_t;
typedef unsigned int uint_t;
typedef __attribute__((ext_vector_type(8))) short short8;
typedef __attribute__((ext_vector_type(4))) float float4v;

static __device__ inline unsigned short f2bf(float f) {   // fp32 -> bf16 RNE
    unsigned u = __float_as_uint(f);
    unsigned r = (u + 0x7FFF + ((u >> 16) & 1)) >> 16;
    return (unsigned short)r;
}
static __device__ inline float bf2f(unsigned short b) {
    return __uint_as_float(((unsigned)b) << 16);
}

// Grid barrier. CRITICAL: poll with an atomic LOAD (read path, no
// serialization), never an RMW — R7's atomicAdd(bar,0) poll saturated the
// same-address atomic unit (~76 RMW/us) and cost ~50 us per barrier.
static __device__ inline void grid_barrier(int* bar, int phase) {
    __syncthreads();
    if (threadIdx.x == 0) {
        __threadfence();                         // release prior writes
        __hip_atomic_fetch_add(bar, 1, __ATOMIC_RELEASE, __HIP_MEMORY_SCOPE_AGENT);
        int target = GRID * (phase + 1);
        while (__hip_atomic_load(bar, __ATOMIC_ACQUIRE, __HIP_MEMORY_SCOPE_AGENT) < target)
            __builtin_amdgcn_s_sleep(16);
        __threadfence();                         // acquire others' writes
    }
    __syncthreads();
}

// ---------------------------------------------------------------------------
// Mega-kernel: phase A (gemm T16 + hist + v3) | barrier | scan1 | barrier |
//              scan2 | barrier | fill.  512 blocks, all co-resident.
// ---------------------------------------------------------------------------
__global__ __launch_bounds__(256, 2)
void mega_kernel(const float* __restrict__ emb,
                 const float* __restrict__ W2,
                 const float* __restrict__ W3,
                 const float* __restrict__ W4,
                 const int* __restrict__ ei,
                 const float* __restrict__ attr,
                 ushort_t* __restrict__ T16,
                 int* __restrict__ cnt,
                 ushort_t* __restrict__ rank16,
                 int* __restrict__ off,
                 int* __restrict__ bases,
                 int* __restrict__ bsums,
                 float* __restrict__ v3,
                 uint_t* __restrict__ packed,
                 int* __restrict__ bar) {
    __shared__ int smem_i[8192];                 // 32 KB, reused per phase
    short8* sblob = (short8*)smem_i;

    int t    = threadIdx.x;
    int b    = blockIdx.x;
    int wave = t >> 6;
    int lane = t & 63;
    int n16  = lane & 15;
    int quad = lane >> 4;

    // ---- phase A.1: stage W2 fragment blob into LDS ----
#pragma unroll
    for (int i = 0; i < 8; ++i) {
        int f  = wave * 8 + i;                   // 0..31
        int ct = f >> 2, ki = f & 3;
        short8 fr;
#pragma unroll
        for (int j = 0; j < 8; ++j) {
            int k = ki * 32 + quad * 8 + j;
            fr[j] = (short)f2bf(W2[k * HD + ct * 16 + n16]);
        }
        sblob[f * 64 + lane] = fr;
    }
    __syncthreads();

    short8 bfrag[8][4];
#pragma unroll
    for (int ct = 0; ct < 8; ++ct)
#pragma unroll
        for (int ki = 0; ki < 4; ++ki)
            bfrag[ct][ki] = sblob[(ct * 4 + ki) * 64 + lane];

    // ---- phase A.2: gemm tiles, grid-stride ----
    for (int tt = b; tt < NTILES; tt += GRID) {
        int rowbase = tt * 64 + wave * 16;
        int row  = rowbase + n16;
        int rowc = row < N_NODES ? row : N_NODES - 1;
        const float4* arow = (const float4*)(emb + (size_t)rowc * HD);

        short8 afrag[4];
#pragma unroll
        for (int ki = 0; ki < 4; ++ki) {
            float4 lo = arow[ki * 8 + quad * 2];
            float4 hi = arow[ki * 8 + quad * 2 + 1];
            short8 a;
            a[0] = (short)f2bf(lo.x); a[1] = (short)f2bf(lo.y);
            a[2] = (short)f2bf(lo.z); a[3] = (short)f2bf(lo.w);
            a[4] = (short)f2bf(hi.x); a[5] = (short)f2bf(hi.y);
            a[6] = (short)f2bf(hi.z); a[7] = (short)f2bf(hi.w);
            afrag[ki] = a;
        }

        float4v acc[8];
#pragma unroll
        for (int ct = 0; ct < 8; ++ct) acc[ct] = (float4v){0.f, 0.f, 0.f, 0.f};

#pragma unroll
        for (int ki = 0; ki < 4; ++ki)
#pragma unroll
            for (int ct = 0; ct < 8; ++ct)
                acc[ct] = __builtin_amdgcn_mfma_f32_16x16x32_bf16(
                    afrag[ki], bfrag[ct][ki], acc[ct], 0, 0, 0);

        // C/D layout: col = lane&15, row = quad*4 + reg
#pragma unroll
        for (int reg = 0; reg < 4; ++reg) {
            int r = rowbase + quad * 4 + reg;
            if (r < N_NODES) {
#pragma unroll
                for (int ct = 0; ct < 8; ++ct)
                    T16[(size_t)r * HD + ct * 16 + n16] = f2bf(acc[ct][reg]);
            }
        }
    }

    // ---- phase A.3: hist chunks, grid-stride ----
    for (int c = b; c < N_HIST_BLOCKS; c += GRID) {
        int e = c * 256 + t;
        int rep = c & (NREP - 1);
        int r = ei[e];
        int rank = atomicAdd(&cnt[rep * N_NODES + r], 1);
        rank16[e] = (ushort_t)rank;
    }

    // ---- phase A.4: v3 = relu(W4) @ W3 (one block) ----
    if (b == 300 && t < HD) {
        float acc = 0.f;
        for (int k = 0; k < HD; ++k) {
            float w = W4[k];
            w = w > 0.f ? w : 0.f;
            acc += w * W3[k * HD + t];
        }
        v3[t] = acc;
    }

    grid_barrier(bar, 0);

    // ---- scan1: group b covers nodes [b*256, b*256+256) ----
    if (b < N_SCAN_BLOCKS) {
        int n = b * 256 + t;
        int c[NREP];
        int tsum = 0;
#pragma unroll
        for (int r = 0; r < NREP; ++r) {
            c[r] = (n < N_NODES) ? cnt[r * N_NODES + n] : 0;
            tsum += c[r];
        }
        smem_i[t] = tsum;
        __syncthreads();
        for (int o = 1; o < 256; o <<= 1) {
            int add = (t >= o) ? smem_i[t - o] : 0;
            __syncthreads();
            smem_i[t] += add;
            __syncthreads();
        }
        int ex = smem_i[t] - tsum;               // block-local exclusive
        if (n < N_NODES) {
            off[n] = ex;
            int run = ex;
#pragma unroll
            for (int r = 0; r < NREP; ++r) {
                bases[r * N_NODES + n] = run;
                run += c[r];
            }
        }
        if (t == 255) bsums[b] = smem_i[255];
    }

    grid_barrier(bar, 1);

    // ---- scan2: block 0 exclusive-scans the 196 block sums ----
    if (b == 0) {
        int v = (t < N_SCAN_BLOCKS) ? bsums[t] : 0;
        smem_i[t] = v;
        __syncthreads();
        for (int o = 1; o < 256; o <<= 1) {
            int add = (t >= o) ? smem_i[t - o] : 0;
            __syncthreads();
            smem_i[t] += add;
            __syncthreads();
        }
        if (t < N_SCAN_BLOCKS) bsums[t] = smem_i[t] - v;   // exclusive
    }

    grid_barrier(bar, 2);

    // ---- fill: place packed (attr_bf16 << 16 | col), no atomics ----
    for (int c = b; c < N_HIST_BLOCKS; c += GRID) {
        int e = c * 256 + t;
        int rep = c & (NREP - 1);
        int r = ei[e];
        int pos = bases[rep * N_NODES + r] + bsums[r >> 8] + (int)rank16[e];
        uint_t p = ((uint_t)f2bf(attr[e]) << 16) | (uint_t)ei[N_EDGES + e];
        packed[pos] = p;
    }
}

// ---------------------------------------------------------------------------
// Owner-computes: out[n] = relu( x[n]@W1 + sum_c T16[c] + (sum attr)*v3 )
// 16 lanes/node, ushort8 per lane per neighbor row; 8 gathers in flight.
// ---------------------------------------------------------------------------
__global__ void aggregate_kernel(const int* __restrict__ off,
                                 const int* __restrict__ bsums,
                                 const uint_t* __restrict__ packed,
                                 const ushort_t* __restrict__ T16,
                                 const float* __restrict__ x,
                                 const float* __restrict__ W1,
                                 const float* __restrict__ v3,
                                 float* __restrict__ out) {
    int tid  = blockIdx.x * 256 + threadIdx.x;
    int node = tid >> 4;                 // 16 nodes per block
    int lane = tid & 15;                 // owns cols [8*lane, 8*lane+8)
    int s  = off[node] + bsums[node >> 8];
    int e1 = (node + 1 == N_NODES) ? N_EDGES
                                   : off[node + 1] + bsums[(node + 1) >> 8];
    int deg = e1 - s;

    float acc[8];
#pragma unroll
    for (int i = 0; i < 8; ++i) acc[i] = 0.f;
    float ssum = 0.f;

    for (int base = 0; base < deg; base += 16) {
        int rem = deg - base; if (rem > 16) rem = 16;
        uint_t p = 0;
        if (lane < rem) p = packed[s + base + lane];
        ssum += __uint_as_float(p & 0xFFFF0000u);    // attr bf16-hi, +0 if idle
        int col = (int)(p & 0xFFFFu);
        int j = 0;
        for (; j + 8 <= rem; j += 8) {
            short8 tv[8];
#pragma unroll
            for (int q = 0; q < 8; ++q) {
                int c = __shfl(col, j + q, 16);
                tv[q] = ((const short8*)(T16 + (size_t)c * HD))[lane];
            }
#pragma unroll
            for (int i = 0; i < 8; ++i)
                acc[i] += ((bf2f((ushort_t)tv[0][i]) + bf2f((ushort_t)tv[1][i]))
                         + (bf2f((ushort_t)tv[2][i]) + bf2f((ushort_t)tv[3][i])))
                        + ((bf2f((ushort_t)tv[4][i]) + bf2f((ushort_t)tv[5][i]))
                         + (bf2f((ushort_t)tv[6][i]) + bf2f((ushort_t)tv[7][i])));
        }
        for (; j < rem; ++j) {
            int c = __shfl(col, j, 16);
            short8 tv = ((const short8*)(T16 + (size_t)c * HD))[lane];
#pragma unroll
            for (int i = 0; i < 8; ++i)
                acc[i] += bf2f((ushort_t)tv[i]);
        }
    }
    for (int o = 8; o; o >>= 1) ssum += __shfl_xor(ssum, o, 16);

    const float4* v3p = (const float4*)v3;
    float4 b0 = v3p[lane * 2], b1 = v3p[lane * 2 + 1];
    acc[0] += ssum * b0.x; acc[1] += ssum * b0.y;
    acc[2] += ssum * b0.z; acc[3] += ssum * b0.w;
    acc[4] += ssum * b1.x; acc[5] += ssum * b1.y;
    acc[6] += ssum * b1.z; acc[7] += ssum * b1.w;
#pragma unroll
    for (int i = 0; i < IN_DIM; ++i) {
        float xi = x[node * IN_DIM + i];
        const float4* wp = (const float4*)(W1 + i * HD);
        float4 w0 = wp[lane * 2], w1 = wp[lane * 2 + 1];
        acc[0] += xi * w0.x; acc[1] += xi * w0.y;
        acc[2] += xi * w0.z; acc[3] += xi * w0.w;
        acc[4] += xi * w1.x; acc[5] += xi * w1.y;
        acc[6] += xi * w1.z; acc[7] += xi * w1.w;
    }
    float4 o0, o1;
    o0.x = fmaxf(acc[0], 0.f); o0.y = fmaxf(acc[1], 0.f);
    o0.z = fmaxf(acc[2], 0.f); o0.w = fmaxf(acc[3], 0.f);
    o1.x = fmaxf(acc[4], 0.f); o1.y = fmaxf(acc[5], 0.f);
    o1.z = fmaxf(acc[6], 0.f); o1.w = fmaxf(acc[7], 0.f);
    float4* op = (float4*)(out + (size_t)node * HD);
    op[lane * 2]     = o0;
    op[lane * 2 + 1] = o1;
}

extern "C" void kernel_launch(void* const* d_in, const int* in_sizes, int n_in,
                              void* d_out, int out_size, void* d_ws, size_t ws_size,
                              hipStream_t stream) {
    const float* x    = (const float*)d_in[0];   // [N,8]
    const int*   ei   = (const int*)  d_in[1];   // [2,E]
    const float* attr = (const float*)d_in[2];   // [E,1]
    const float* emb  = (const float*)d_in[3];   // [N,128]
    const float* W1   = (const float*)d_in[4];   // [8,128]
    const float* W2   = (const float*)d_in[5];   // [128,128]
    const float* W3   = (const float*)d_in[6];   // [128,128]
    const float* W4   = (const float*)d_in[7];   // [1,128]
    float* out = (float*)d_out;                  // [N,128]

    // workspace layout (~24.3 MB)
    char* w = (char*)d_ws;
    uint_t*   packed = (uint_t*)w;                                   // 3.2 MB
    ushort_t* T16    = (ushort_t*)(w + (size_t)N_EDGES * 4);         // 12.8 MB
    int*      off    = (int*)((char*)T16 + (size_t)N_NODES * HD * 2);
    int*      bases  = off + N_NODES + 4;        // NREP * N_NODES   // 3.2 MB
    int*      cnt    = bases + NREP * N_NODES;   // NREP * N_NODES   // 3.2 MB
    int*      bar    = cnt + NREP * N_NODES;     // barrier counter (16 ints)
    int*      bsums  = bar + 16;                 // 256
    float*    v3     = (float*)(bsums + 256);    // 128
    ushort_t* rank16 = (ushort_t*)(v3 + HD);     // 1.6 MB

    // zero cnt AND the adjacent barrier words in one memset
    hipMemsetAsync(cnt, 0, (size_t)NREP * N_NODES * sizeof(int) + 16 * sizeof(int), stream);

    mega_kernel<<<GRID, 256, 0, stream>>>(emb, W2, W3, W4, ei, attr,
                                          T16, cnt, rank16, off, bases,
                                          bsums, v3, packed, bar);
    aggregate_kernel<<<(N_NODES * 16) / 256, 256, 0, stream>>>(
        off, bsums, packed, T16, x, W1, v3, out);
}

// Round 9
// 199.717 us; speedup vs baseline: 1.9826x; 1.9826x over previous
//
#include <hip/hip_runtime.h>

#define N_NODES 50000
#define N_EDGES 800000
#define IN_DIM  8
#define HD      128
#define N_SCAN_BLOCKS ((N_NODES + 255) / 256)   // 196
#define NREP 16
#define NTILES ((N_NODES + 63) / 64)            // 782 row-tiles of 64
#define N_HIST_BLOCKS (N_EDGES / 256)           // 3125
#define GRID_P1 (NTILES * 5)                    // 3910: 1 gemm per 4 hist

typedef unsigned short ushort_t;
typedef unsigned int uint_t;
typedef __attribute__((ext_vector_type(8))) short short8;
typedef __attribute__((ext_vector_type(4))) float float4v;

static __device__ inline unsigned short f2bf(float f) {   // fp32 -> bf16 RNE
    unsigned u = __float_as_uint(f);
    unsigned r = (u + 0x7FFF + ((u >> 16) & 1)) >> 16;
    return (unsigned short)r;
}
static __device__ inline float bf2f(unsigned short b) {
    return __uint_as_float(((unsigned)b) << 16);
}

// ---------------------------------------------------------------------------
// One-block prep: bf16 B-fragment blob for the MFMA gemm.
// ---------------------------------------------------------------------------
__global__ void prep_kernel(const float* __restrict__ W2,
                            short8* __restrict__ blob) {
    int t = threadIdx.x;                 // 0..255
#pragma unroll
    for (int i = 0; i < 8; ++i) {
        int slot = t * 8 + i;            // 0..2047
        int f    = slot >> 6;            // 0..31
        int lane = slot & 63;
        int ct = f >> 2, ki = f & 3;
        int n16 = lane & 15, quad = lane >> 4;
        short8 fr;
#pragma unroll
        for (int j = 0; j < 8; ++j) {
            int k = ki * 32 + quad * 8 + j;
            fr[j] = (short)f2bf(W2[k * HD + ct * 16 + n16]);
        }
        blob[slot] = fr;
    }
}

// ---------------------------------------------------------------------------
// Fused phase 1: blockIdx%5==0 -> gemm tile (MFMA, BW-bound);
//                else          -> hist chunk (atomic-latency-bound).
// ---------------------------------------------------------------------------
__global__ __launch_bounds__(256, 2)
void phase1_kernel(const float* __restrict__ emb,
                   const short8* __restrict__ blob,
                   ushort_t* __restrict__ T16,
                   const int* __restrict__ ei,
                   int* __restrict__ cnt,
                   ushort_t* __restrict__ rank16) {
    __shared__ short8 sblob[2048];       // 32 KB
    int sel = blockIdx.x % 5;

    if (sel != 0) {
        // ---- hist path: chunk c covers edges [c*256, c*256+256) ----
        int c = (blockIdx.x / 5) * 4 + sel - 1;
        if (c >= N_HIST_BLOCKS) return;
        int e = c * 256 + threadIdx.x;
        int rep = c & (NREP - 1);
        int r = ei[e];
        int rank = atomicAdd(&cnt[rep * N_NODES + r], 1);
        rank16[e] = (ushort_t)rank;
        return;
    }

    // ---- gemm path ----
    int tt   = blockIdx.x / 5;           // 0..781
    int t    = threadIdx.x;
    int wave = t >> 6;
    int lane = t & 63;
    int n16  = lane & 15;
    int quad = lane >> 4;

#pragma unroll
    for (int i = 0; i < 8; ++i)          // coalesced 32 KB copy
        sblob[t * 8 + i] = blob[t * 8 + i];
    __syncthreads();

    short8 bfrag[8][4];
#pragma unroll
    for (int ct = 0; ct < 8; ++ct)
#pragma unroll
        for (int ki = 0; ki < 4; ++ki)
            bfrag[ct][ki] = sblob[(ct * 4 + ki) * 64 + lane];

    int rowbase = tt * 64 + wave * 16;
    int row  = rowbase + n16;
    int rowc = row < N_NODES ? row : N_NODES - 1;
    const float4* arow = (const float4*)(emb + (size_t)rowc * HD);

    short8 afrag[4];
#pragma unroll
    for (int ki = 0; ki < 4; ++ki) {
        float4 lo = arow[ki * 8 + quad * 2];
        float4 hi = arow[ki * 8 + quad * 2 + 1];
        short8 a;
        a[0] = (short)f2bf(lo.x); a[1] = (short)f2bf(lo.y);
        a[2] = (short)f2bf(lo.z); a[3] = (short)f2bf(lo.w);
        a[4] = (short)f2bf(hi.x); a[5] = (short)f2bf(hi.y);
        a[6] = (short)f2bf(hi.z); a[7] = (short)f2bf(hi.w);
        afrag[ki] = a;
    }

    float4v acc[8];
#pragma unroll
    for (int ct = 0; ct < 8; ++ct) acc[ct] = (float4v){0.f, 0.f, 0.f, 0.f};

#pragma unroll
    for (int ki = 0; ki < 4; ++ki)
#pragma unroll
        for (int ct = 0; ct < 8; ++ct)
            acc[ct] = __builtin_amdgcn_mfma_f32_16x16x32_bf16(
                afrag[ki], bfrag[ct][ki], acc[ct], 0, 0, 0);

    // C/D layout: col = lane&15 (within tile), row = quad*4 + reg
#pragma unroll
    for (int reg = 0; reg < 4; ++reg) {
        int r = rowbase + quad * 4 + reg;
        if (r < N_NODES) {
#pragma unroll
            for (int ct = 0; ct < 8; ++ct)
                T16[(size_t)r * HD + ct * 16 + n16] = f2bf(acc[ct][reg]);
        }
    }
}

// ---------------------------------------------------------------------------
// Fused scan: blocks 0..195 do scan1 (block-local off/bases + bsums);
// block 196 computes v3; the LAST scan block to finish (done-counter,
// one RMW per block — NO polling) exclusive-scans bsums.
// bsums crosses an intra-kernel block boundary -> AGENT-scope atomics
// (L2-bypass) for cross-XCD visibility.
// ---------------------------------------------------------------------------
__global__ void scan_kernel(const int* __restrict__ cnt,
                            int* __restrict__ off,
                            int* __restrict__ bases,
                            int* __restrict__ bsums,
                            int* __restrict__ done,
                            const float* __restrict__ W4,
                            const float* __restrict__ W3,
                            float* __restrict__ v3) {
    __shared__ int lds[256];
    __shared__ int is_last;
    int t = threadIdx.x;
    int b = blockIdx.x;

    if (b == N_SCAN_BLOCKS) {            // ---- v3 = relu(W4) @ W3 ----
        if (t < HD) {
            float acc = 0.f;
            for (int k = 0; k < HD; ++k) {
                float w = W4[k];
                w = w > 0.f ? w : 0.f;
                acc += w * W3[k * HD + t];
            }
            v3[t] = acc;
        }
        return;
    }

    // ---- scan1 ----
    int n = b * 256 + t;
    int c[NREP];
    int tsum = 0;
#pragma unroll
    for (int r = 0; r < NREP; ++r) {
        c[r] = (n < N_NODES) ? cnt[r * N_NODES + n] : 0;
        tsum += c[r];
    }
    lds[t] = tsum;
    __syncthreads();
    for (int o = 1; o < 256; o <<= 1) {
        int add = (t >= o) ? lds[t - o] : 0;
        __syncthreads();
        lds[t] += add;
        __syncthreads();
    }
    int ex = lds[t] - tsum;              // block-local exclusive
    if (n < N_NODES) {
        off[n] = ex;
        int run = ex;
#pragma unroll
        for (int r = 0; r < NREP; ++r) {
            bases[r * N_NODES + n] = run;
            run += c[r];
        }
    }
    if (t == 255)
        __hip_atomic_store(&bsums[b], lds[255], __ATOMIC_RELEASE,
                           __HIP_MEMORY_SCOPE_AGENT);
    __syncthreads();

    // ---- last-block-done: one RMW per block, no polling ----
    if (t == 0) {
        int prev = __hip_atomic_fetch_add(done, 1, __ATOMIC_ACQ_REL,
                                          __HIP_MEMORY_SCOPE_AGENT);
        is_last = (prev == N_SCAN_BLOCKS - 1);
    }
    __syncthreads();
    if (!is_last) return;

    // ---- scan2 (runs in the last-finishing block) ----
    int v = (t < N_SCAN_BLOCKS)
          ? __hip_atomic_load(&bsums[t], __ATOMIC_ACQUIRE,
                              __HIP_MEMORY_SCOPE_AGENT)
          : 0;
    __syncthreads();                     // lds[] reuse
    lds[t] = v;
    __syncthreads();
    for (int o = 1; o < 256; o <<= 1) {
        int add = (t >= o) ? lds[t - o] : 0;
        __syncthreads();
        lds[t] += add;
        __syncthreads();
    }
    if (t < N_SCAN_BLOCKS) bsums[t] = lds[t] - v;   // exclusive; next kernel reads
}

// ---------------------------------------------------------------------------
// Pass 2: place packed (attr_bf16 << 16 | col) -- NO atomics.
// ---------------------------------------------------------------------------
__global__ void fill_kernel(const int* __restrict__ ei,
                            const float* __restrict__ attr,
                            const ushort_t* __restrict__ rank16,
                            const int* __restrict__ bases,
                            const int* __restrict__ bsums,
                            uint_t* __restrict__ packed) {
    int e = blockIdx.x * 256 + threadIdx.x;
    int rep = (e >> 8) & (NREP - 1);     // == chunk & (NREP-1)
    int r = ei[e];
    int pos = bases[rep * N_NODES + r] + bsums[r >> 8] + (int)rank16[e];
    uint_t p = ((uint_t)f2bf(attr[e]) << 16) | (uint_t)ei[N_EDGES + e];
    packed[pos] = p;
}

// ---------------------------------------------------------------------------
// Owner-computes: out[n] = relu( x[n]@W1 + sum_c T16[c] + (sum attr)*v3 )
// 16 lanes/node, ushort8 per lane per neighbor row; 8 gathers in flight.
// ---------------------------------------------------------------------------
__global__ void aggregate_kernel(const int* __restrict__ off,
                                 const int* __restrict__ bsums,
                                 const uint_t* __restrict__ packed,
                                 const ushort_t* __restrict__ T16,
                                 const float* __restrict__ x,
                                 const float* __restrict__ W1,
                                 const float* __restrict__ v3,
                                 float* __restrict__ out) {
    int tid  = blockIdx.x * 256 + threadIdx.x;
    int node = tid >> 4;                 // 16 nodes per block
    int lane = tid & 15;                 // owns cols [8*lane, 8*lane+8)
    int s  = off[node] + bsums[node >> 8];
    int e1 = (node + 1 == N_NODES) ? N_EDGES
                                   : off[node + 1] + bsums[(node + 1) >> 8];
    int deg = e1 - s;

    float acc[8];
#pragma unroll
    for (int i = 0; i < 8; ++i) acc[i] = 0.f;
    float ssum = 0.f;

    for (int base = 0; base < deg; base += 16) {
        int rem = deg - base; if (rem > 16) rem = 16;
        uint_t p = 0;
        if (lane < rem) p = packed[s + base + lane];
        ssum += __uint_as_float(p & 0xFFFF0000u);    // attr bf16-hi, +0 if idle
        int col = (int)(p & 0xFFFFu);
        int j = 0;
        for (; j + 8 <= rem; j += 8) {
            short8 tv[8];
#pragma unroll
            for (int q = 0; q < 8; ++q) {
                int c = __shfl(col, j + q, 16);
                tv[q] = ((const short8*)(T16 + (size_t)c * HD))[lane];
            }
#pragma unroll
            for (int i = 0; i < 8; ++i)
                acc[i] += ((bf2f((ushort_t)tv[0][i]) + bf2f((ushort_t)tv[1][i]))
                         + (bf2f((ushort_t)tv[2][i]) + bf2f((ushort_t)tv[3][i])))
                        + ((bf2f((ushort_t)tv[4][i]) + bf2f((ushort_t)tv[5][i]))
                         + (bf2f((ushort_t)tv[6][i]) + bf2f((ushort_t)tv[7][i])));
        }
        for (; j < rem; ++j) {
            int c = __shfl(col, j, 16);
            short8 tv = ((const short8*)(T16 + (size_t)c * HD))[lane];
#pragma unroll
            for (int i = 0; i < 8; ++i)
                acc[i] += bf2f((ushort_t)tv[i]);
        }
    }
    for (int o = 8; o; o >>= 1) ssum += __shfl_xor(ssum, o, 16);

    const float4* v3p = (const float4*)v3;
    float4 b0 = v3p[lane * 2], b1 = v3p[lane * 2 + 1];
    acc[0] += ssum * b0.x; acc[1] += ssum * b0.y;
    acc[2] += ssum * b0.z; acc[3] += ssum * b0.w;
    acc[4] += ssum * b1.x; acc[5] += ssum * b1.y;
    acc[6] += ssum * b1.z; acc[7] += ssum * b1.w;
#pragma unroll
    for (int i = 0; i < IN_DIM; ++i) {
        float xi = x[node * IN_DIM + i];
        const float4* wp = (const float4*)(W1 + i * HD);
        float4 w0 = wp[lane * 2], w1 = wp[lane * 2 + 1];
        acc[0] += xi * w0.x; acc[1] += xi * w0.y;
        acc[2] += xi * w0.z; acc[3] += xi * w0.w;
        acc[4] += xi * w1.x; acc[5] += xi * w1.y;
        acc[6] += xi * w1.z; acc[7] += xi * w1.w;
    }
    float4 o0, o1;
    o0.x = fmaxf(acc[0], 0.f); o0.y = fmaxf(acc[1], 0.f);
    o0.z = fmaxf(acc[2], 0.f); o0.w = fmaxf(acc[3], 0.f);
    o1.x = fmaxf(acc[4], 0.f); o1.y = fmaxf(acc[5], 0.f);
    o1.z = fmaxf(acc[6], 0.f); o1.w = fmaxf(acc[7], 0.f);
    float4* op = (float4*)(out + (size_t)node * HD);
    op[lane * 2]     = o0;
    op[lane * 2 + 1] = o1;
}

extern "C" void kernel_launch(void* const* d_in, const int* in_sizes, int n_in,
                              void* d_out, int out_size, void* d_ws, size_t ws_size,
                              hipStream_t stream) {
    const float* x    = (const float*)d_in[0];   // [N,8]
    const int*   ei   = (const int*)  d_in[1];   // [2,E]
    const float* attr = (const float*)d_in[2];   // [E,1]
    const float* emb  = (const float*)d_in[3];   // [N,128]
    const float* W1   = (const float*)d_in[4];   // [8,128]
    const float* W2   = (const float*)d_in[5];   // [128,128]
    const float* W3   = (const float*)d_in[6];   // [128,128]
    const float* W4   = (const float*)d_in[7];   // [1,128]
    float* out = (float*)d_out;                  // [N,128]

    // workspace layout (~24.3 MB)
    char* w = (char*)d_ws;
    uint_t*   packed = (uint_t*)w;                                   // 3.2 MB
    ushort_t* T16    = (ushort_t*)(w + (size_t)N_EDGES * 4);         // 12.8 MB
    short8*   blob   = (short8*)((char*)T16 + (size_t)N_NODES * HD * 2); // 32 KB
    int*      off    = (int*)((char*)blob + 2048 * 16);              // N+4
    int*      bases  = off + N_NODES + 4;        // NREP * N_NODES   // 3.2 MB
    int*      cnt    = bases + NREP * N_NODES;   // NREP * N_NODES   // 3.2 MB
    int*      done   = cnt + NREP * N_NODES;     // 16 ints (zeroed w/ cnt)
    int*      bsums  = done + 16;                // 256
    float*    v3     = (float*)(bsums + 256);    // 128
    ushort_t* rank16 = (ushort_t*)(v3 + HD);     // 1.6 MB

    // zero cnt AND the adjacent done counter in one memset
    hipMemsetAsync(cnt, 0, (size_t)NREP * N_NODES * sizeof(int) + 16 * sizeof(int), stream);

    prep_kernel  <<<1, 256, 0, stream>>>(W2, blob);
    phase1_kernel<<<GRID_P1, 256, 0, stream>>>(emb, blob, T16, ei, cnt, rank16);
    scan_kernel  <<<N_SCAN_BLOCKS + 1, 256, 0, stream>>>(cnt, off, bases, bsums,
                                                         done, W4, W3, v3);
    fill_kernel  <<<N_HIST_BLOCKS, 256, 0, stream>>>(ei, attr, rank16, bases, bsums, packed);
    aggregate_kernel<<<(N_NODES * 16) / 256, 256, 0, stream>>>(
        off, bsums, packed, T16, x, W1, v3, out);
}

// Round 10
// 189.325 us; speedup vs baseline: 2.0914x; 1.0549x over previous
//
#include <hip/hip_runtime.h>

#define N_NODES 50000
#define N_EDGES 800000
#define IN_DIM  8
#define HD      128
#define N_SCAN_BLOCKS ((N_NODES + 255) / 256)   // 196
#define NREP 16
#define NTILES ((N_NODES + 63) / 64)            // 782 row-tiles of 64
#define N_HIST_BLOCKS (N_EDGES / 256)           // 3125
#define GRID_P1 (NTILES * 5)                    // 3910: 1 gemm per 4 hist

typedef unsigned short ushort_t;
typedef unsigned int uint_t;
typedef __attribute__((ext_vector_type(8))) short short8;
typedef __attribute__((ext_vector_type(4))) float float4v;

static __device__ inline unsigned short f2bf(float f) {   // fp32 -> bf16 RNE
    unsigned u = __float_as_uint(f);
    unsigned r = (u + 0x7FFF + ((u >> 16) & 1)) >> 16;
    return (unsigned short)r;
}
static __device__ inline float bf2f(unsigned short b) {
    return __uint_as_float(((unsigned)b) << 16);
}

// ---------------------------------------------------------------------------
// Prep + zero fused: blocks 0..195 zero cnt (int4 stores, replaces the
// hipMemsetAsync dispatch); block 196 builds the bf16 W2 fragment blob.
// ---------------------------------------------------------------------------
__global__ void prep_zero_kernel(const float* __restrict__ W2,
                                 short8* __restrict__ blob,
                                 int4* __restrict__ cnt4) {
    int b = blockIdx.x;
    int t = threadIdx.x;

    if (b < N_SCAN_BLOCKS) {             // ---- zero cnt: 200000 int4 total ----
#pragma unroll
        for (int i = 0; i < 4; ++i) {
            int idx = b * 1024 + i * 256 + t;
            if (idx < (NREP * N_NODES) / 4)
                cnt4[idx] = make_int4(0, 0, 0, 0);
        }
        return;
    }

    // ---- blob: fragment f=ct*4+ki, lane; elem j = bf16(W2[(ki*32+quad*8+j)*HD + ct*16+n16])
#pragma unroll
    for (int i = 0; i < 8; ++i) {
        int slot = t * 8 + i;            // 0..2047
        int f    = slot >> 6;            // 0..31
        int lane = slot & 63;
        int ct = f >> 2, ki = f & 3;
        int n16 = lane & 15, quad = lane >> 4;
        short8 fr;
#pragma unroll
        for (int j = 0; j < 8; ++j) {
            int k = ki * 32 + quad * 8 + j;
            fr[j] = (short)f2bf(W2[k * HD + ct * 16 + n16]);
        }
        blob[slot] = fr;
    }
}

// ---------------------------------------------------------------------------
// Fused phase 1: blockIdx%5==0 -> gemm tile (MFMA, BW-bound);
//                else          -> hist chunk (atomic-latency-bound).
// ---------------------------------------------------------------------------
__global__ __launch_bounds__(256, 2)
void phase1_kernel(const float* __restrict__ emb,
                   const short8* __restrict__ blob,
                   ushort_t* __restrict__ T16,
                   const int* __restrict__ ei,
                   int* __restrict__ cnt,
                   ushort_t* __restrict__ rank16) {
    __shared__ short8 sblob[2048];       // 32 KB
    int sel = blockIdx.x % 5;

    if (sel != 0) {
        // ---- hist path: chunk c covers edges [c*256, c*256+256) ----
        int c = (blockIdx.x / 5) * 4 + sel - 1;
        if (c >= N_HIST_BLOCKS) return;
        int e = c * 256 + threadIdx.x;
        int rep = c & (NREP - 1);
        int r = ei[e];
        int rank = atomicAdd(&cnt[rep * N_NODES + r], 1);
        rank16[e] = (ushort_t)rank;
        return;
    }

    // ---- gemm path ----
    int tt   = blockIdx.x / 5;           // 0..781
    int t    = threadIdx.x;
    int wave = t >> 6;
    int lane = t & 63;
    int n16  = lane & 15;
    int quad = lane >> 4;

#pragma unroll
    for (int i = 0; i < 8; ++i)          // coalesced 32 KB copy
        sblob[t * 8 + i] = blob[t * 8 + i];
    __syncthreads();

    short8 bfrag[8][4];
#pragma unroll
    for (int ct = 0; ct < 8; ++ct)
#pragma unroll
        for (int ki = 0; ki < 4; ++ki)
            bfrag[ct][ki] = sblob[(ct * 4 + ki) * 64 + lane];

    int rowbase = tt * 64 + wave * 16;
    int row  = rowbase + n16;
    int rowc = row < N_NODES ? row : N_NODES - 1;
    const float4* arow = (const float4*)(emb + (size_t)rowc * HD);

    short8 afrag[4];
#pragma unroll
    for (int ki = 0; ki < 4; ++ki) {
        float4 lo = arow[ki * 8 + quad * 2];
        float4 hi = arow[ki * 8 + quad * 2 + 1];
        short8 a;
        a[0] = (short)f2bf(lo.x); a[1] = (short)f2bf(lo.y);
        a[2] = (short)f2bf(lo.z); a[3] = (short)f2bf(lo.w);
        a[4] = (short)f2bf(hi.x); a[5] = (short)f2bf(hi.y);
        a[6] = (short)f2bf(hi.z); a[7] = (short)f2bf(hi.w);
        afrag[ki] = a;
    }

    float4v acc[8];
#pragma unroll
    for (int ct = 0; ct < 8; ++ct) acc[ct] = (float4v){0.f, 0.f, 0.f, 0.f};

#pragma unroll
    for (int ki = 0; ki < 4; ++ki)
#pragma unroll
        for (int ct = 0; ct < 8; ++ct)
            acc[ct] = __builtin_amdgcn_mfma_f32_16x16x32_bf16(
                afrag[ki], bfrag[ct][ki], acc[ct], 0, 0, 0);

    // C/D layout: col = lane&15 (within tile), row = quad*4 + reg
#pragma unroll
    for (int reg = 0; reg < 4; ++reg) {
        int r = rowbase + quad * 4 + reg;
        if (r < N_NODES) {
#pragma unroll
            for (int ct = 0; ct < 8; ++ct)
                T16[(size_t)r * HD + ct * 16 + n16] = f2bf(acc[ct][reg]);
        }
    }
}

// ---------------------------------------------------------------------------
// Scan: per-node totals over reps; BLOCK-LOCAL exclusive off[] + bases[];
// global fixup (bsums) applied by consumers on the fly.
// ---------------------------------------------------------------------------
__global__ void scan1_kernel(const int* __restrict__ cnt,
                             int* __restrict__ off,
                             int* __restrict__ bases,
                             int* __restrict__ blocksums) {
    __shared__ int lds[256];
    int t = threadIdx.x;
    int n = blockIdx.x * 256 + t;
    int c[NREP];
    int tsum = 0;
#pragma unroll
    for (int r = 0; r < NREP; ++r) {
        c[r] = (n < N_NODES) ? cnt[r * N_NODES + n] : 0;
        tsum += c[r];
    }
    lds[t] = tsum;
    __syncthreads();
    for (int o = 1; o < 256; o <<= 1) {
        int add = (t >= o) ? lds[t - o] : 0;
        __syncthreads();
        lds[t] += add;
        __syncthreads();
    }
    int ex = lds[t] - tsum;              // exclusive prefix within block
    if (n < N_NODES) {
        off[n] = ex;
        int run = ex;
#pragma unroll
        for (int r = 0; r < NREP; ++r) {
            bases[r * N_NODES + n] = run;
            run += c[r];
        }
    }
    if (t == 255) blocksums[blockIdx.x] = lds[255];
}

// block 0: exclusive scan of blocksums; block 1: v3 = relu(W4) @ W3
__global__ void scan2_v3_kernel(int* __restrict__ blocksums,
                                const float* __restrict__ W4,
                                const float* __restrict__ W3,
                                float* __restrict__ v3) {
    int t = threadIdx.x;
    if (blockIdx.x == 1) {
        if (t < HD) {
            float acc = 0.f;
            for (int k = 0; k < HD; ++k) {
                float w = W4[k];
                w = w > 0.f ? w : 0.f;
                acc += w * W3[k * HD + t];
            }
            v3[t] = acc;
        }
        return;
    }
    __shared__ int lds[256];
    int v = (t < N_SCAN_BLOCKS) ? blocksums[t] : 0;
    lds[t] = v;
    __syncthreads();
    for (int o = 1; o < 256; o <<= 1) {
        int add = (t >= o) ? lds[t - o] : 0;
        __syncthreads();
        lds[t] += add;
        __syncthreads();
    }
    if (t < N_SCAN_BLOCKS) blocksums[t] = lds[t] - v;   // exclusive
}

// ---------------------------------------------------------------------------
// Pass 2: place packed (attr_bf16 << 16 | col) -- NO atomics.
// ---------------------------------------------------------------------------
__global__ void fill_kernel(const int* __restrict__ ei,
                            const float* __restrict__ attr,
                            const ushort_t* __restrict__ rank16,
                            const int* __restrict__ bases,
                            const int* __restrict__ bsums,
                            uint_t* __restrict__ packed) {
    int e = blockIdx.x * 256 + threadIdx.x;
    int rep = (e >> 8) & (NREP - 1);     // == chunk & (NREP-1)
    int r = ei[e];
    int pos = bases[rep * N_NODES + r] + bsums[r >> 8] + (int)rank16[e];
    uint_t p = ((uint_t)f2bf(attr[e]) << 16) | (uint_t)ei[N_EDGES + e];
    packed[pos] = p;
}

// ---------------------------------------------------------------------------
// Owner-computes: out[n] = relu( x[n]@W1 + sum_c T16[c] + (sum attr)*v3 )
// 16 lanes/node, ushort8 (16 B) per lane per neighbor row; MLP-4 gathers.
// (unroll-4, VGPR=28: R9's unroll-8 regressed — occupancy > ILP here)
// ---------------------------------------------------------------------------
__global__ void aggregate_kernel(const int* __restrict__ off,
                                 const int* __restrict__ bsums,
                                 const uint_t* __restrict__ packed,
                                 const ushort_t* __restrict__ T16,
                                 const float* __restrict__ x,
                                 const float* __restrict__ W1,
                                 const float* __restrict__ v3,
                                 float* __restrict__ out) {
    int tid  = blockIdx.x * 256 + threadIdx.x;
    int node = tid >> 4;                 // 16 nodes per block
    int lane = tid & 15;                 // owns cols [8*lane, 8*lane+8)
    int s  = off[node] + bsums[node >> 8];
    int e1 = (node + 1 == N_NODES) ? N_EDGES
                                   : off[node + 1] + bsums[(node + 1) >> 8];
    int deg = e1 - s;

    float acc[8];
#pragma unroll
    for (int i = 0; i < 8; ++i) acc[i] = 0.f;
    float ssum = 0.f;

    for (int base = 0; base < deg; base += 16) {
        int rem = deg - base; if (rem > 16) rem = 16;
        uint_t p = 0;
        if (lane < rem) p = packed[s + base + lane];
        ssum += __uint_as_float(p & 0xFFFF0000u);    // attr bf16-hi, +0 if idle
        int col = (int)(p & 0xFFFFu);
        int j = 0;
        for (; j + 4 <= rem; j += 4) {
            int c0 = __shfl(col, j + 0, 16);
            int c1 = __shfl(col, j + 1, 16);
            int c2 = __shfl(col, j + 2, 16);
            int c3 = __shfl(col, j + 3, 16);
            short8 t0 = ((const short8*)(T16 + (size_t)c0 * HD))[lane];
            short8 t1 = ((const short8*)(T16 + (size_t)c1 * HD))[lane];
            short8 t2 = ((const short8*)(T16 + (size_t)c2 * HD))[lane];
            short8 t3 = ((const short8*)(T16 + (size_t)c3 * HD))[lane];
#pragma unroll
            for (int i = 0; i < 8; ++i)
                acc[i] += (bf2f((ushort_t)t0[i]) + bf2f((ushort_t)t1[i]))
                        + (bf2f((ushort_t)t2[i]) + bf2f((ushort_t)t3[i]));
        }
        for (; j < rem; ++j) {
            int c = __shfl(col, j, 16);
            short8 tv = ((const short8*)(T16 + (size_t)c * HD))[lane];
#pragma unroll
            for (int i = 0; i < 8; ++i)
                acc[i] += bf2f((ushort_t)tv[i]);
        }
    }
    // reduce ssum across the 16-lane group
    for (int o = 8; o; o >>= 1) ssum += __shfl_xor(ssum, o, 16);

    const float4* v3p = (const float4*)v3;
    float4 b0 = v3p[lane * 2], b1 = v3p[lane * 2 + 1];
    acc[0] += ssum * b0.x; acc[1] += ssum * b0.y;
    acc[2] += ssum * b0.z; acc[3] += ssum * b0.w;
    acc[4] += ssum * b1.x; acc[5] += ssum * b1.y;
    acc[6] += ssum * b1.z; acc[7] += ssum * b1.w;
#pragma unroll
    for (int i = 0; i < IN_DIM; ++i) {
        float xi = x[node * IN_DIM + i];
        const float4* wp = (const float4*)(W1 + i * HD);
        float4 w0 = wp[lane * 2], w1 = wp[lane * 2 + 1];
        acc[0] += xi * w0.x; acc[1] += xi * w0.y;
        acc[2] += xi * w0.z; acc[3] += xi * w0.w;
        acc[4] += xi * w1.x; acc[5] += xi * w1.y;
        acc[6] += xi * w1.z; acc[7] += xi * w1.w;
    }
    float4 o0, o1;
    o0.x = fmaxf(acc[0], 0.f); o0.y = fmaxf(acc[1], 0.f);
    o0.z = fmaxf(acc[2], 0.f); o0.w = fmaxf(acc[3], 0.f);
    o1.x = fmaxf(acc[4], 0.f); o1.y = fmaxf(acc[5], 0.f);
    o1.z = fmaxf(acc[6], 0.f); o1.w = fmaxf(acc[7], 0.f);
    float4* op = (float4*)(out + (size_t)node * HD);
    op[lane * 2]     = o0;
    op[lane * 2 + 1] = o1;
}

extern "C" void kernel_launch(void* const* d_in, const int* in_sizes, int n_in,
                              void* d_out, int out_size, void* d_ws, size_t ws_size,
                              hipStream_t stream) {
    const float* x    = (const float*)d_in[0];   // [N,8]
    const int*   ei   = (const int*)  d_in[1];   // [2,E]
    const float* attr = (const float*)d_in[2];   // [E,1]
    const float* emb  = (const float*)d_in[3];   // [N,128]
    const float* W1   = (const float*)d_in[4];   // [8,128]
    const float* W2   = (const float*)d_in[5];   // [128,128]
    const float* W3   = (const float*)d_in[6];   // [128,128]
    const float* W4   = (const float*)d_in[7];   // [1,128]
    float* out = (float*)d_out;                  // [N,128]

    // workspace layout (~24.3 MB)
    char* w = (char*)d_ws;
    uint_t*   packed = (uint_t*)w;                                   // 3.2 MB
    ushort_t* T16    = (ushort_t*)(w + (size_t)N_EDGES * 4);         // 12.8 MB
    short8*   blob   = (short8*)((char*)T16 + (size_t)N_NODES * HD * 2); // 32 KB
    int*      off    = (int*)((char*)blob + 2048 * 16);              // N+4
    int*      bases  = off + N_NODES + 4;        // NREP * N_NODES   // 3.2 MB
    int*      cnt    = bases + NREP * N_NODES;   // NREP * N_NODES   // 3.2 MB
    int*      bsums  = cnt + NREP * N_NODES;     // 256
    float*    v3     = (float*)(bsums + 256);    // 128
    ushort_t* rank16 = (ushort_t*)(v3 + HD);     // 1.6 MB

    prep_zero_kernel<<<N_SCAN_BLOCKS + 1, 256, 0, stream>>>(W2, blob, (int4*)cnt);
    phase1_kernel<<<GRID_P1, 256, 0, stream>>>(emb, blob, T16, ei, cnt, rank16);
    scan1_kernel <<<N_SCAN_BLOCKS, 256, 0, stream>>>(cnt, off, bases, bsums);
    scan2_v3_kernel<<<2, 256, 0, stream>>>(bsums, W4, W3, v3);
    fill_kernel  <<<N_HIST_BLOCKS, 256, 0, stream>>>(ei, attr, rank16, bases, bsums, packed);
    aggregate_kernel<<<(N_NODES * 16) / 256, 256, 0, stream>>>(
        off, bsums, packed, T16, x, W1, v3, out);
}